// Round 4
// baseline (1190.922 us; speedup 1.0000x reference)
//
#include <hip/hip_runtime.h>
#include <hip/hip_bf16.h>

// Problem dims (fixed)
#define Bdim 16
#define Sdim 512
#define Ddim 512
#define Hdim 8
#define DKdim 64
#define Fdim 2048
#define Mrows (Bdim * Sdim)   // 8192

typedef __attribute__((ext_vector_type(8))) short  frag16;   // 8 bf16 (4 VGPRs)
typedef __attribute__((ext_vector_type(4))) float  f32x4;    // MFMA acc
typedef __attribute__((ext_vector_type(8))) unsigned short ushort8;
typedef __attribute__((ext_vector_type(4))) unsigned short ushort4v;

// round-to-nearest-even fp32 -> bf16 (finite data)
__device__ __forceinline__ unsigned short f2b(float x) {
    union { float f; unsigned int u; } v; v.f = x;
    unsigned int r = (v.u + 0x7FFFu + ((v.u >> 16) & 1u)) >> 16;
    return (unsigned short)r;
}
__device__ __forceinline__ float b2f(unsigned short u) {
    union { float f; unsigned int i; } v; v.i = ((unsigned int)u) << 16;
    return v.f;
}

// ---------------------------------------------------------------------------
// bf16 MFMA GEMM (m97 structure): C[M,N] = A[M,K] @ Bt[N,K]^T + bias
// 128x128 tile, BK=32, 256 threads (4 waves), wave = 64x64, 4x4 MFMA tiles.
// trans_out: write bf16 output transposed as Vt[b,h,d,s] (for V projection).
// ---------------------------------------------------------------------------
__global__ __launch_bounds__(256) void gemm_mfma(
    const __hip_bfloat16* __restrict__ A,   // [M,K] bf16
    const __hip_bfloat16* __restrict__ Bt,  // [N,K] bf16 (transposed weights)
    const float* __restrict__ bias,         // [N]
    const float* __restrict__ R,            // [M,N] fp32 residual or null
    float* __restrict__ Cf,                 // [M,N] fp32 out or null
    unsigned short* __restrict__ Cb,        // bf16 out or null
    int M, int N, int K, int do_relu, int trans_out)
{
    __shared__ short As[128 * 32];
    __shared__ short Bs[128 * 32];

    const int t = threadIdx.x;
    const int lane = t & 63;
    const int wave = t >> 6;
    const int bm = blockIdx.y * 128;
    const int bn = blockIdx.x * 128;
    const int wm = (wave >> 1) * 64;
    const int wn = (wave & 1) * 64;

    f32x4 acc[4][4] = {};

    const int lrow = lane >> 2;
    const int lcol = (lane & 3) * 8;

    for (int k0 = 0; k0 < K; k0 += 32) {
#pragma unroll
        for (int i = 0; i < 2; ++i) {
            const int chunk = wave * 2 + i;
            const int row = chunk * 16 + lrow;
            const __hip_bfloat16* ga = A + (size_t)(bm + row) * K + k0 + lcol;
            const __hip_bfloat16* gb = Bt + (size_t)(bn + row) * K + k0 + lcol;
            __builtin_amdgcn_global_load_lds(
                (const __attribute__((address_space(1))) unsigned int*)ga,
                (__attribute__((address_space(3))) unsigned int*)(As + chunk * 512),
                16, 0, 0);
            __builtin_amdgcn_global_load_lds(
                (const __attribute__((address_space(1))) unsigned int*)gb,
                (__attribute__((address_space(3))) unsigned int*)(Bs + chunk * 512),
                16, 0, 0);
        }
        __syncthreads();

        const int fr = lane & 15;
        const int quad = lane >> 4;
        frag16 af[4], bfr[4];
#pragma unroll
        for (int i = 0; i < 4; ++i) {
            af[i]  = *(const frag16*)(As + (wm + i * 16 + fr) * 32 + quad * 8);
            bfr[i] = *(const frag16*)(Bs + (wn + i * 16 + fr) * 32 + quad * 8);
        }
#pragma unroll
        for (int mi = 0; mi < 4; ++mi)
#pragma unroll
            for (int ni = 0; ni < 4; ++ni)
                acc[mi][ni] = __builtin_amdgcn_mfma_f32_16x16x32_bf16(
                    af[mi], bfr[ni], acc[mi][ni], 0, 0, 0);
        __syncthreads();
    }

    const int fr = lane & 15;
    const int quad = lane >> 4;

    if (trans_out) {
        // V projection: write Vt[b, h, d, s] bf16; m=(b,s), n=(h,d)
#pragma unroll
        for (int mi = 0; mi < 4; ++mi)
#pragma unroll
            for (int ni = 0; ni < 4; ++ni) {
                const int m = bm + wm + mi * 16 + quad * 4;
                const int n = bn + wn + ni * 16 + fr;
                ushort4v o;
#pragma unroll
                for (int r = 0; r < 4; ++r) o[r] = f2b(acc[mi][ni][r] + bias[n]);
                const int bb = m >> 9, s = m & 511;
                const int hh = n >> 6, dd = n & 63;
                *(ushort4v*)(Cb + (((size_t)((bb * Hdim + hh) * DKdim + dd)) << 9) + s) = o;
            }
        return;
    }

#pragma unroll
    for (int mi = 0; mi < 4; ++mi) {
#pragma unroll
        for (int r = 0; r < 4; ++r) {
            const int m = bm + wm + mi * 16 + quad * 4 + r;
#pragma unroll
            for (int ni = 0; ni < 4; ++ni) {
                const int n = bn + wn + ni * 16 + fr;
                float v = acc[mi][ni][r] + bias[n];
                if (R) v += R[(size_t)m * N + n];
                if (do_relu) v = fmaxf(v, 0.f);
                if (Cf) Cf[(size_t)m * N + n] = v;
                if (Cb) Cb[(size_t)m * N + n] = f2b(v);
            }
        }
    }
}

// ---------------------------------------------------------------------------
// fp32 -> bf16 convert, 8 elems/thread
// ---------------------------------------------------------------------------
__global__ __launch_bounds__(256) void conv_b(
    const float* __restrict__ X, unsigned short* __restrict__ Y)
{
    const size_t i = ((size_t)blockIdx.x * 256 + threadIdx.x) * 8;
    float4 a = *(const float4*)(X + i);
    float4 b = *(const float4*)(X + i + 4);
    ushort8 o;
    o[0] = f2b(a.x); o[1] = f2b(a.y); o[2] = f2b(a.z); o[3] = f2b(a.w);
    o[4] = f2b(b.x); o[5] = f2b(b.y); o[6] = f2b(b.z); o[7] = f2b(b.w);
    *(ushort8*)(Y + i) = o;
}

// ---------------------------------------------------------------------------
// Weight transpose+convert: W[K,N] fp32 -> Wt[N,K] bf16. 64x64 tiles.
// ---------------------------------------------------------------------------
__global__ __launch_bounds__(256) void wtrans(
    const float* __restrict__ W, unsigned short* __restrict__ Wt, int K, int N)
{
    __shared__ float T[64][65];
    const int n0 = blockIdx.x * 64, k0 = blockIdx.y * 64;
    const int t = threadIdx.x;
    const int kl = t >> 4, n4 = (t & 15) << 2;
#pragma unroll
    for (int it = 0; it < 4; ++it) {
        const int k = kl + it * 16;
        float4 v = *(const float4*)(W + (size_t)(k0 + k) * N + n0 + n4);
        T[n4 + 0][k] = v.x; T[n4 + 1][k] = v.y;
        T[n4 + 2][k] = v.z; T[n4 + 3][k] = v.w;
    }
    __syncthreads();
    const int nl = t >> 3, k8 = (t & 7) << 3;
#pragma unroll
    for (int it = 0; it < 2; ++it) {
        const int n = nl + it * 32;
        ushort8 o;
#pragma unroll
        for (int c = 0; c < 8; ++c) o[c] = f2b(T[n][k8 + c]);
        *(ushort8*)(Wt + (size_t)(n0 + n) * K + k0 + k8) = o;
    }
}

// ---------------------------------------------------------------------------
// MFMA monotonic attention. One (b,h) per block, 4 waves x 16 q-rows.
// QK^T, triangular suffix-cumsum, and PV all on the matrix pipe.
// Per-wave 16x512 bf16 LDS prob buffer, XOR-swizzled in 16B blocks.
// ---------------------------------------------------------------------------
#define SWZ(q, j) (((q) << 9) + ((((j) >> 3) ^ (q)) << 3) + ((j) & 7))

__global__ __launch_bounds__(256, 2) void attn_mfma(
    const unsigned short* __restrict__ Kb,   // [B*S, D] bf16 (Q == K)
    const unsigned short* __restrict__ Vt,   // [B,H,DK,S] bf16
    const float* __restrict__ gam,
    unsigned short* __restrict__ Ob,         // [B*S, D] bf16
    int mask_type)
{
    __shared__ unsigned short P[4][16 * 512];   // 64 KB

    const int qt = blockIdx.x, h = blockIdx.y, b = blockIdx.z;
    const int t = threadIdx.x, lane = t & 63, w = t >> 6;
    const int quad = lane >> 4, fr = lane & 15;
    const int q0 = qt * 64 + w * 16;
    unsigned short* Pw = P[w];

    const unsigned short* kbase = Kb + ((size_t)b * Sdim) * Ddim + h * DKdim;

    // Q A-frags (row = q0+fr, k-chunks 0/32 at quad*8)
    frag16 aq0 = *(const frag16*)(kbase + (size_t)(q0 + fr) * Ddim + quad * 8);
    frag16 aq1 = *(const frag16*)(kbase + (size_t)(q0 + fr) * Ddim + 32 + quad * 8);

    // ---- QK^T: 32 j-tiles x 2 MFMA
    f32x4 sc[32];
#pragma unroll
    for (int jn = 0; jn < 32; ++jn) {
        frag16 b0 = *(const frag16*)(kbase + (size_t)(jn * 16 + fr) * Ddim + quad * 8);
        frag16 b1 = *(const frag16*)(kbase + (size_t)(jn * 16 + fr) * Ddim + 32 + quad * 8);
        f32x4 z = {0.f, 0.f, 0.f, 0.f};
        z = __builtin_amdgcn_mfma_f32_16x16x32_bf16(aq0, b0, z, 0, 0, 0);
        z = __builtin_amdgcn_mfma_f32_16x16x32_bf16(aq1, b1, z, 0, 0, 0);
        sc[jn] = z;
    }

    // ---- scale + mask + softmax-1 (e1 unnormalized, stored bf16 to LDS)
    const float NEG = -1e32f;
    float m1[4] = {NEG, NEG, NEG, NEG};
#pragma unroll
    for (int jn = 0; jn < 32; ++jn)
#pragma unroll
        for (int r = 0; r < 4; ++r) {
            const int qg = q0 + quad * 4 + r;
            const int jg = jn * 16 + fr;
            const bool valid = mask_type ? (jg <= qg) : (jg < qg);
            const float v = valid ? sc[jn][r] * 0.125f : NEG;
            sc[jn][r] = v;
            m1[r] = fmaxf(m1[r], v);
        }
#pragma unroll
    for (int r = 0; r < 4; ++r)
#pragma unroll
        for (int o = 1; o <= 8; o <<= 1) m1[r] = fmaxf(m1[r], __shfl_xor(m1[r], o));

    float sum1[4] = {0.f, 0.f, 0.f, 0.f};
#pragma unroll
    for (int jn = 0; jn < 32; ++jn)
#pragma unroll
        for (int r = 0; r < 4; ++r) {
            const int qg = q0 + quad * 4 + r;
            const int jg = jn * 16 + fr;
            const bool valid = mask_type ? (jg <= qg) : (jg < qg);
            const float e = __expf(sc[jn][r] - m1[r]);
            sum1[r] += e;
            Pw[SWZ(quad * 4 + r, jg)] = f2b(valid ? e : 0.f);
        }
#pragma unroll
    for (int r = 0; r < 4; ++r)
#pragma unroll
        for (int o = 1; o <= 8; o <<= 1) sum1[r] += __shfl_xor(sum1[r], o);
    __syncthreads();

    // ---- suffix-cumsum via MFMA with in-register triangular B-frags
    // T'[k][n] = 1 iff k > n  ->  suffix(j) = sum_{j' > j} e1[j']  (exact 0 at diag)
    frag16 ONESF, BEV, BOD;
#pragma unroll
    for (int i = 0; i < 8; ++i) {
        ONESF[i] = (short)0x3F80;
        BEV[i] = (quad * 8 + i > fr)      ? (short)0x3F80 : (short)0;
        BOD[i] = (quad * 8 + i > fr + 16) ? (short)0x3F80 : (short)0;
    }
    frag16 pa[16];
#pragma unroll
    for (int kt = 0; kt < 16; ++kt)
        pa[kt] = *(const frag16*)(Pw + (fr << 9) + (((kt * 4 + quad) ^ fr) << 3));

    const f32x4 zz = {0.f, 0.f, 0.f, 0.f};
#pragma unroll
    for (int jn = 0; jn < 32; ++jn) {
        const int fb = jn >> 1;
        f32x4 z = __builtin_amdgcn_mfma_f32_16x16x32_bf16(
            pa[fb], (jn & 1) ? BOD : BEV, zz, 0, 0, 0);
#pragma unroll
        for (int kt = 0; kt < 16; ++kt)
            if (kt > fb)
                z = __builtin_amdgcn_mfma_f32_16x16x32_bf16(pa[kt], ONESF, z, 0, 0, 0);
        sc[jn] = z;   // unnormalized suffix sums (overwrites scores)
    }

    // ---- decay + second softmax (scores rebuilt: s = m1 + ln(e1))
    const float gneg = -log1pf(__expf(gam[h]));   // -softplus(gamma)
    float rs1[4], m2[4] = {NEG, NEG, NEG, NEG};
#pragma unroll
    for (int r = 0; r < 4; ++r) rs1[r] = 1.f / sum1[r];
#pragma unroll
    for (int jn = 0; jn < 32; ++jn)
#pragma unroll
        for (int r = 0; r < 4; ++r) {
            const int qg = q0 + quad * 4 + r;
            const int jg = jn * 16 + fr;
            const bool valid = mask_type ? (jg <= qg) : (jg < qg);
            const float e1v = b2f(Pw[SWZ(quad * 4 + r, jg)]);
            const float s = m1[r] + __logf(e1v);
            const float suffix = sc[jn][r] * rs1[r];
            const int dd = qg - jg;
            const float pos = (float)(dd >= 0 ? dd : -dd);
            const float dist = sqrtf(fmaxf(suffix * pos, 0.f));
            float te = __expf(dist * gneg);
            te = fminf(fmaxf(te, 1e-5f), 1e5f);
            const float s2 = valid ? s * te : NEG;
            sc[jn][r] = s2;
            m2[r] = fmaxf(m2[r], s2);
        }
#pragma unroll
    for (int r = 0; r < 4; ++r)
#pragma unroll
        for (int o = 1; o <= 8; o <<= 1) m2[r] = fmaxf(m2[r], __shfl_xor(m2[r], o));

    float sum2[4] = {0.f, 0.f, 0.f, 0.f};
#pragma unroll
    for (int jn = 0; jn < 32; ++jn)
#pragma unroll
        for (int r = 0; r < 4; ++r) {
            const float e = __expf(sc[jn][r] - m2[r]);
            sc[jn][r] = e;
            sum2[r] += e;
        }
#pragma unroll
    for (int r = 0; r < 4; ++r)
#pragma unroll
        for (int o = 1; o <= 8; o <<= 1) sum2[r] += __shfl_xor(sum2[r], o);
    float rs2[4];
#pragma unroll
    for (int r = 0; r < 4; ++r) rs2[r] = 1.f / sum2[r];
#pragma unroll
    for (int jn = 0; jn < 32; ++jn)
#pragma unroll
        for (int r = 0; r < 4; ++r)
            Pw[SWZ(quad * 4 + r, jn * 16 + fr)] = f2b(sc[jn][r] * rs2[r]);
    __syncthreads();

    // ---- PV via MFMA: O[q][d] = P2 @ V
    const unsigned short* vtb = Vt + ((size_t)(b * Hdim + h) * DKdim) * Sdim;
    f32x4 acc[4];
#pragma unroll
    for (int dt = 0; dt < 4; ++dt) acc[dt] = zz;
#pragma unroll
    for (int kt = 0; kt < 16; ++kt) {
        frag16 pf = *(const frag16*)(Pw + (fr << 9) + (((kt * 4 + quad) ^ fr) << 3));
#pragma unroll
        for (int dt = 0; dt < 4; ++dt) {
            frag16 vf = *(const frag16*)(vtb + (size_t)(dt * 16 + fr) * Sdim + kt * 32 + quad * 8);
            acc[dt] = __builtin_amdgcn_mfma_f32_16x16x32_bf16(pf, vf, acc[dt], 0, 0, 0);
        }
    }
    unsigned short* obase = Ob + ((size_t)(b * Sdim + q0)) * Ddim + h * DKdim;
#pragma unroll
    for (int dt = 0; dt < 4; ++dt)
#pragma unroll
        for (int r = 0; r < 4; ++r)
            obase[(size_t)(quad * 4 + r) * Ddim + dt * 16 + fr] = f2b(acc[dt][r]);
}

// ---------------------------------------------------------------------------
// LayerNorm over last dim (512); fp32 out (nullable) + bf16 out (nullable).
// ---------------------------------------------------------------------------
__global__ __launch_bounds__(256) void ln_kernel(
    const float* __restrict__ X, const float* __restrict__ g,
    const float* __restrict__ bta, float* __restrict__ Y,
    unsigned short* __restrict__ Yb)
{
    const int row = blockIdx.x;
    const int t = threadIdx.x;
    __shared__ float r1[256], r2[256];
    const float* x = X + (size_t)row * Ddim;
    float a = x[t], b = x[t + 256];
    r1[t] = a + b;
    r2[t] = a * a + b * b;
    __syncthreads();
    for (int off = 128; off; off >>= 1) {
        if (t < off) { r1[t] += r1[t + off]; r2[t] += r2[t + off]; }
        __syncthreads();
    }
    float mean = r1[0] * (1.f / Ddim);
    float var = r2[0] * (1.f / Ddim) - mean * mean;
    float rs = rsqrtf(var + 1e-5f);
    float y0 = (a - mean) * rs * g[t] + bta[t];
    float y1 = (b - mean) * rs * g[t + 256] + bta[t + 256];
    if (Y) {
        float* y = Y + (size_t)row * Ddim;
        y[t] = y0;
        y[t + 256] = y1;
    }
    if (Yb) {
        unsigned short* yb = Yb + (size_t)row * Ddim;
        yb[t] = f2b(y0);
        yb[t + 256] = f2b(y1);
    }
}

// ---------------------------------------------------------------------------
extern "C" void kernel_launch(void* const* d_in, const int* in_sizes, int n_in,
                              void* d_out, int out_size, void* d_ws, size_t ws_size,
                              hipStream_t stream)
{
    const float* x0     = (const float*)d_in[0];
    const float* y0     = (const float*)d_in[1];
    const float* Wk     = (const float*)d_in[2];
    const float* bk     = (const float*)d_in[3];
    const float* Wv     = (const float*)d_in[4];
    const float* bv     = (const float*)d_in[5];
    const float* Wo     = (const float*)d_in[6];
    const float* bo     = (const float*)d_in[7];
    const float* gammas = (const float*)d_in[8];
    const float* ln1g   = (const float*)d_in[9];
    const float* ln1b   = (const float*)d_in[10];
    const float* W1     = (const float*)d_in[11];
    const float* b1     = (const float*)d_in[12];
    const float* W2     = (const float*)d_in[13];
    const float* b2     = (const float*)d_in[14];
    const float* ln2g   = (const float*)d_in[15];
    const float* ln2b   = (const float*)d_in[16];

    const size_t NBSD = (size_t)Mrows * Ddim;   // 4,194,304
    float* ws = (float*)d_ws;
    float* T1   = ws;
    float* X1   = T1 + NBSD;
    float* Xbuf = X1 + NBSD;
    unsigned short* Kbf = (unsigned short*)(Xbuf + NBSD);
    unsigned short* Vt  = Kbf + NBSD;
    unsigned short* AOb = Vt + NBSD;
    unsigned short* Abf = AOb + NBSD;
    unsigned short* Xbf = Abf + NBSD;
    unsigned short* Ybf = Xbf + NBSD;
    unsigned short* Hbb = Ybf + NBSD;                      // [M,F]
    unsigned short* Wta = Hbb + (size_t)Mrows * Fdim;
    unsigned short* Wtb = Wta + (size_t)Fdim * Ddim;

    const dim3 gDD(Ddim / 128, Mrows / 128);
    const dim3 gDF(Fdim / 128, Mrows / 128);
    const int convBlocks = (int)(NBSD / 2048);

    auto run_block = [&](int l, const float* qinf, const unsigned short* qinb,
                         const unsigned short* vinb, int mask_type, bool ffn,
                         float* outf, unsigned short* outb) {
        const float* Wk_l = Wk + (size_t)l * Ddim * Ddim;
        const float* bk_l = bk + (size_t)l * Ddim;
        const float* Wv_l = Wv + (size_t)l * Ddim * Ddim;
        const float* bv_l = bv + (size_t)l * Ddim;
        const float* Wo_l = Wo + (size_t)l * Ddim * Ddim;
        const float* bo_l = bo + (size_t)l * Ddim;

        // K (=Q) projection -> bf16 only
        wtrans<<<dim3(8, 8), 256, 0, stream>>>(Wk_l, Wta, Ddim, Ddim);
        gemm_mfma<<<gDD, 256, 0, stream>>>((const __hip_bfloat16*)qinb,
            (const __hip_bfloat16*)Wta, bk_l, nullptr, nullptr, Kbf,
            Mrows, Ddim, Ddim, 0, 0);
        // V projection -> transposed bf16 Vt[b,h,d,s]
        wtrans<<<dim3(8, 8), 256, 0, stream>>>(Wv_l, Wtb, Ddim, Ddim);
        gemm_mfma<<<gDD, 256, 0, stream>>>((const __hip_bfloat16*)vinb,
            (const __hip_bfloat16*)Wtb, bv_l, nullptr, nullptr, Vt,
            Mrows, Ddim, Ddim, 0, 1);
        // attention (MFMA) -> bf16 AOb
        attn_mfma<<<dim3(Sdim / 64, Hdim, Bdim), 256, 0, stream>>>(
            Kbf, Vt, gammas + (size_t)l * Hdim, AOb, mask_type);
        // O-projection + residual -> T1 (fp32); LN1
        wtrans<<<dim3(8, 8), 256, 0, stream>>>(Wo_l, Wta, Ddim, Ddim);
        gemm_mfma<<<gDD, 256, 0, stream>>>((const __hip_bfloat16*)AOb,
            (const __hip_bfloat16*)Wta, bo_l, qinf, T1, nullptr,
            Mrows, Ddim, Ddim, 0, 0);
        float* x1f = ffn ? X1 : outf;
        unsigned short* x1b = ffn ? Abf : outb;
        ln_kernel<<<Mrows, 256, 0, stream>>>(T1,
            ln1g + (size_t)l * Ddim, ln1b + (size_t)l * Ddim, x1f, x1b);
        if (ffn) {
            const float* W1_l = W1 + (size_t)l * Ddim * Fdim;
            const float* b1_l = b1 + (size_t)l * Fdim;
            const float* W2_l = W2 + (size_t)l * Fdim * Ddim;
            const float* b2_l = b2 + (size_t)l * Ddim;
            wtrans<<<dim3(32, 8), 256, 0, stream>>>(W1_l, Wtb, Ddim, Fdim);
            gemm_mfma<<<gDF, 256, 0, stream>>>((const __hip_bfloat16*)Abf,
                (const __hip_bfloat16*)Wtb, b1_l, nullptr, nullptr, Hbb,
                Mrows, Fdim, Ddim, 1, 0);
            wtrans<<<dim3(8, 32), 256, 0, stream>>>(W2_l, Wta, Fdim, Ddim);
            gemm_mfma<<<gDD, 256, 0, stream>>>((const __hip_bfloat16*)Hbb,
                (const __hip_bfloat16*)Wta, b2_l, X1, T1, nullptr,
                Mrows, Ddim, Fdim, 0, 0);
            ln_kernel<<<Mrows, 256, 0, stream>>>(T1,
                ln2g + (size_t)l * Ddim, ln2b + (size_t)l * Ddim, outf, outb);
        }
    };

    // Block 0: knowledge encoder (y), mask1, FFN -> Ybf (bf16 only)
    conv_b<<<convBlocks, 256, 0, stream>>>(y0, Abf);
    run_block(0, y0, Abf, Abf, 1, true, nullptr, Ybf);
    // Block 1: question encoder (x), mask1, no FFN -> Xbuf/Xbf
    conv_b<<<convBlocks, 256, 0, stream>>>(x0, Abf);
    run_block(1, x0, Abf, Abf, 1, false, Xbuf, Xbf);
    // Block 2: knowledge retriever, q/k=x, v=y, mask0, FFN -> d_out (fp32)
    run_block(2, Xbuf, Xbf, Ybf, 0, true, (float*)d_out, nullptr);
}